// Round 13
// baseline (26.260 us; speedup 1.0000x reference)
//
#include <hip/hip_runtime.h>

// Problem constants (match reference)
#define BATCH 4
#define QLEN 2048
#define CLEN 2048
#define DIM 512
#define CPB 256             // partial chunks per batch (8 rows each)
#define NSL 8               // e-slices in middle kernel

// The reference collapses: einsum 'bqkh,bvha->bqha' has independent k and v,
// and softmax over k sums to exactly 1, so
//   out[b,q,:] = ((sum_cl context[b,cl,:]) @ Wkv[:,D:2D]) @ Wout   for every q.
// query, Wq, mask are dead inputs.
//
// R12 (NT streams, 24.96us) minus: 1 graph node (k3+k4 fused via opart slice
// trick), K1's LDS round-trip (thread-owned column sums), K5's per-block
// fixed costs (16-row blocks). In-kernel grid sync is dead (R3/4/7/11).

typedef float f32x4 __attribute__((ext_vector_type(4)));

// ---- K1: partial[c][d] = colsum of chunk c's 8 context rows (16.8 MB NT
// read). 512 blocks x 2 chunks; no LDS, no syncthreads. ----
__global__ __launch_bounds__(256) void k1_partial(const float* __restrict__ ctx,
                                                  f32x4* __restrict__ partial) {
    const int t = threadIdx.x;
    const int c = blockIdx.x * 2 + (t >> 7);       // chunk 0..1023
    const int f4 = t & 127;
    const f32x4* src = reinterpret_cast<const f32x4*>(ctx)
                     + (size_t)c * 8 * (DIM / 4) + f4;
    f32x4 s0 = {0.f, 0.f, 0.f, 0.f}, s1 = {0.f, 0.f, 0.f, 0.f};
#pragma unroll
    for (int r = 0; r < 8; r += 2) {               // 8 independent NT loads
        s0 += __builtin_nontemporal_load(&src[(size_t)r * (DIM / 4)]);
        s1 += __builtin_nontemporal_load(&src[(size_t)(r + 1) * (DIM / 4)]);
    }
    partial[(size_t)c * (DIM / 4) + f4] = s0 + s1;
}

// ---- K2: csum[b][col4] = sum over 256 chunk partials. 512 blocks, 1 load
// per thread + LDS tree (proven R12 pattern). ----
__global__ __launch_bounds__(256) void k2_reduce(const f32x4* __restrict__ partial,
                                                 f32x4* __restrict__ csum) {
    __shared__ f32x4 red[256];
    const int blk = blockIdx.x, t = threadIdx.x;
    const int b = blk >> 7, f4g = blk & 127;
    red[t] = partial[(size_t)(b * CPB + t) * (DIM / 4) + f4g];
    __syncthreads();
#pragma unroll
    for (int s = 128; s > 0; s >>= 1) {
        if (t < s) red[t] += red[t + s];
        __syncthreads();
    }
    if (t == 0) csum[b * (DIM / 4) + f4g] = red[0];
}

// ---- K3: 32 blocks = b(4) x sl(8): vslice then opart[sl][b][:] (the orow
// contribution of e-slice sl) -- R8's proven middle, minus the csum reduce. ----
__global__ __launch_bounds__(256) void k3_mid(const float* __restrict__ csum,
                                              const float* __restrict__ Wkv,
                                              const float* __restrict__ Wout,
                                              float* __restrict__ opart) {
    __shared__ float cs[DIM];
    __shared__ float vl[256];
    __shared__ float vslice[64];
    const int blk = blockIdx.x, t = threadIdx.x;
    const int b = blk >> 3, sl = blk & 7;
    cs[t] = csum[b * DIM + t];
    cs[t + 256] = csum[b * DIM + t + 256];
    __syncthreads();
    {
        const int el = t & 63, dg = t >> 6;
        const float* w = Wkv + (size_t)(dg * 128) * (2 * DIM) + DIM + sl * 64 + el;
        float s = 0.f;
#pragma unroll 8
        for (int d0 = 0; d0 < 128; ++d0)
            s += cs[dg * 128 + d0] * w[(size_t)d0 * (2 * DIM)];
        vl[t] = s;
    }
    __syncthreads();
    if (t < 64) vslice[t] = vl[t] + vl[t + 64] + vl[t + 128] + vl[t + 192];
    __syncthreads();
#pragma unroll
    for (int half = 0; half < 2; ++half) {
        const int f = half * 256 + t;
        const float* w = Wout + (size_t)(sl * 64) * DIM + f;
        float s = 0.f;
#pragma unroll 8
        for (int e0 = 0; e0 < 64; ++e0) s += vslice[e0] * w[(size_t)e0 * DIM];
        opart[(size_t)(sl * BATCH + b) * DIM + f] = s;
    }
}

// ---- K4: out[b,q,:] = sum_sl opart[sl][b][:] (16.8 MB NT write).
// 512 blocks x 16 rows; 8 L2-hot loads + 8 NT stores per thread. ----
__global__ __launch_bounds__(256) void k4_bcast(const f32x4* __restrict__ opart4,
                                                f32x4* __restrict__ out) {
    const int blk = blockIdx.x, t = threadIdx.x;
    const int b = blk >> 7, qg = blk & 127;
    const int rg = t >> 7, f4 = t & 127;
    f32x4 v = {0.f, 0.f, 0.f, 0.f};
#pragma unroll
    for (int sl = 0; sl < NSL; ++sl)               // 8 independent L2-hot loads
        v += opart4[(size_t)(sl * BATCH + b) * (DIM / 4) + f4];
    f32x4* dst = out + (size_t)(b * QLEN + qg * 16) * (DIM / 4) + f4;
#pragma unroll
    for (int i = 0; i < 8; ++i)                    // rows rg + {0,2,...,14}
        __builtin_nontemporal_store(v, &dst[(size_t)(rg + 2 * i) * (DIM / 4)]);
}

extern "C" void kernel_launch(void* const* d_in, const int* in_sizes, int n_in,
                              void* d_out, int out_size, void* d_ws, size_t ws_size,
                              hipStream_t stream) {
    // inputs: 0=query (unused), 1=context, 2=mask (unused), 3=Wq (unused), 4=Wkv, 5=Wout
    const float* ctx  = (const float*)d_in[1];
    const float* Wkv  = (const float*)d_in[4];
    const float* Wout = (const float*)d_in[5];
    float* ws = (float*)d_ws;
    float* partial = ws;                                   // 1024*DIM = 2 MB
    float* csum    = partial + (size_t)1024 * DIM;         // BATCH*DIM
    float* opart   = csum + BATCH * DIM;                   // NSL*BATCH*DIM = 64 KB
    // no memset: every ws word is written before it is read

    k1_partial<<<512, 256, 0, stream>>>(ctx, (f32x4*)partial);
    k2_reduce<<<512, 256, 0, stream>>>((const f32x4*)partial, (f32x4*)csum);
    k3_mid<<<BATCH * NSL, 256, 0, stream>>>(csum, Wkv, Wout, opart);
    k4_bcast<<<512, 256, 0, stream>>>((const f32x4*)opart, (f32x4*)d_out);
}